// Round 4
// baseline (631.691 us; speedup 1.0000x reference)
//
#include <hip/hip_runtime.h>

#define NSEG   800
#define BATCH  256
#define NFREQ  51
#define NELEM  (BATCH*NFREQ)      // 13056
#define NSAMP  80000
#define NBLK   (2*NSEG)           // 1600 K1 blocks (1 segment each)
#define NJ     16                 // reduce split
#define GPJ    (NSEG/NJ)          // 50 blocks per slab

// ---------------- compile-time trig (double Taylor, exact to fp32) ----------------
constexpr double TCPI  = 3.14159265358979323846264338327950288;
constexpr double TC2PI = 6.28318530717958647692528676655900577;

constexpr double taylor_cos(double y) {   // |y| <= pi
    double y2 = y * y, term = 1.0, sum = 1.0;
    for (int j = 1; j <= 26; ++j) { term *= -y2 / (double)((2*j-1)*(2*j)); sum += term; }
    return sum;
}
constexpr double cos_k(int k) {           // cos(2*pi*k/100)
    return -taylor_cos(TC2PI * (double)(k % 100) / 100.0 - TCPI);
}
constexpr double sin_k(int k) {
    int kk = k % 100;
    return (kk >= 50) ? -taylor_cos(TC2PI * (double)(kk - 50) / 100.0 - TCPI * 0.5)
                      :  taylor_cos(TC2PI * (double)kk        / 100.0 - TCPI * 0.5);
}

struct Tabs { float c[50]; float s[50]; float wA[50]; float wB[51]; };
constexpr Tabs make_tabs() {
    Tabs t{};
    for (int k = 0; k < 50; ++k) {
        t.c[k]  = (float)cos_k(k);
        t.s[k]  = (float)sin_k(k);
        int smp = (k < 25) ? k : k + 50;                 // phase-A sample map
        t.wA[k] = (float)(1.0 - cos_k(smp));             // hann(periodic)*2; wA[0] = 0
    }
    for (int q = 0; q < 51; ++q) t.wB[q] = (float)(1.0 - cos_k(q + 25));
    return t;
}
__device__ const Tabs d_tabs = make_tabs();

// One outer-n DFT step: rotation twiddles, f<->50-f mirror amortization.
__device__ __forceinline__ void dft_step(float xn, float xm, float sgn,
                                         float cd, float sd,
                                         float (&re)[NFREQ], float (&im)[NFREQ])
{
    float u  = xn + xm, v = xn - xm;
    float us = sgn * u;
    float vs = -(sgn * v);
    float c = 1.0f, s = 0.0f;
    re[0]  += u;        // f=0:  cos=1
    re[50] += us;       // f=50: (-1)^n
    #pragma unroll
    for (int fp = 1; fp <= 25; ++fp) {
        float nc = fmaf(-s, sd, c * cd);
        float ns = fmaf( c, sd, s * cd);
        c = nc; s = ns;
        re[fp] = fmaf(u, c, re[fp]);
        im[fp] = fmaf(v, s, im[fp]);
        if (fp < 25) {
            re[50 - fp] = fmaf(us, c, re[50 - fp]);
            im[50 - fp] = fmaf(vs, s, im[50 - fp]);
        }
    }
}

// ---------------- K1: 1 segment/block, rolled-n DFT, transposed epilogue ----------------
// ws: part[1600][13056] | saArr[1600] | pb[2*NJ][13056] | k2out[51][2] (double)
__global__ __launch_bounds__(256, 3) void psd_seg_kernel(
    const float* __restrict__ fake, const float* __restrict__ real,
    float* __restrict__ part, float* __restrict__ saArr)
{
    __shared__ float xs[NELEM];        // 52224 B: x-stage, then L-buffer
    __shared__ float ldsred[4];

    const int bx = blockIdx.x;
    const int a  = bx >= NSEG;
    const int s  = a ? bx - NSEG : bx;
    const int t  = threadIdx.x;
    const float* __restrict__ src = a ? real : fake;

    float re[NFREQ], im[NFREQ];
    #pragma unroll
    for (int f = 0; f < NFREQ; ++f) { re[f] = 0.0f; im[f] = 0.0f; }

    // ---- stage A: samples {0..24}u{75..99} -> xs[row*51+q], q=0..49 (x[0] windows to 0)
    for (int k = t; k < 12800; k += 256) {
        int row = k / 50, q = k - row * 50;
        int smp = (q < 25) ? q : q + 50;
        float raw = src[(size_t)row * NSAMP + s * 100 + smp];
        xs[row * 51 + q] = fmaxf(raw, 1e-6f) * d_tabs.wA[q];
    }
    __syncthreads();
    // ---- DFT phase A: n=1..24 (xn at q=n, xm=x[100-n] at q=50-n)
    {
        const float* lx = xs + t * 51;
        float sgn = -1.0f;                       // (-1)^1
        #pragma unroll 2
        for (int n = 1; n <= 24; ++n) {
            dft_step(lx[n], lx[50 - n], sgn, d_tabs.c[n], d_tabs.s[n], re, im);
            sgn = -sgn;
        }
    }
    __syncthreads();
    // ---- stage B: samples {25..75} -> xs[row*51+q], q=0..50
    for (int k = t; k < NELEM; k += 256) {
        int row = k / 51, q = k - row * 51;
        float raw = src[(size_t)row * NSAMP + s * 100 + 25 + q];
        xs[row * 51 + q] = fmaxf(raw, 1e-6f) * d_tabs.wB[q];
    }
    __syncthreads();
    // ---- DFT phase B: n=25..49 (xn at q=n-25, xm=x[100-n] at q=75-n); x50 at q=25
    float x50;
    {
        const float* lx = xs + t * 51;
        float sgn = -1.0f;                       // (-1)^25
        #pragma unroll 2
        for (int n = 25; n <= 49; ++n) {
            dft_step(lx[n - 25], lx[75 - n], sgn, d_tabs.c[n], d_tabs.s[n], re, im);
            sgn = -sgn;
        }
        x50 = lx[25];
    }
    // ---- PSD -> signed clamp log -> own row of xs (thread-local, no sync needed)
    #pragma unroll
    for (int f = 0; f < NFREQ; ++f) {
        float rr = re[f] + ((f & 1) ? -x50 : x50);
        float p  = fmaf(rr, rr, im[f] * im[f]);
        p        = fmaxf(p, 1e-38f);
        float lv = __logf(p);
        float al = fmaxf(fabsf(lv), 1e-6f);
        xs[t * 51 + f] = (lv > 0.0f) ? al : ((lv < 0.0f) ? -al : 0.0f);
    }
    __syncthreads();
    // ---- transposed epilogue: thread t owns group t = elements {r*256+t}
    float Lv[NFREQ];
    float mn = 1e30f, mx = -1e30f;
    #pragma unroll
    for (int r = 0; r < NFREQ; ++r) {
        float v = xs[r * BATCH + t];
        Lv[r] = v;
        mn = fminf(mn, v);
        mx = fmaxf(mx, v);
    }
    const float inv = 1.0f / (mx - mn);
    float ssq = 0.0f;
    float* __restrict__ dst = part + (size_t)bx * NELEM + t;
    #pragma unroll
    for (int r = 0; r < NFREQ; ++r) {
        float F = (Lv[r] - mn) * inv;
        ssq = fmaf(F, F, ssq);
        dst[(size_t)r * BATCH] = F;               // coalesced 1KB/wave stores
    }

    // ---- block-reduce ssq ----
    #pragma unroll
    for (int off = 32; off; off >>= 1) ssq += __shfl_down(ssq, off, 64);
    if ((t & 63) == 0) ldsred[t >> 6] = ssq;
    __syncthreads();
    if (t == 0) saArr[bx] = ldsred[0] + ldsred[1] + ldsred[2] + ldsred[3];
}

// ---------------- K2a: partial column sums over 50-block slabs ----------------
__global__ void reduce_part_kernel(const float* __restrict__ part, float* __restrict__ pb)
{
    const int e = blockIdx.x * 256 + threadIdx.x;   // < 13056
    const int j = blockIdx.y;                        // < NJ
    const float* __restrict__ pF = part + (size_t)(j * GPJ) * NELEM + e;
    const float* __restrict__ pR = part + (size_t)(NSEG + j * GPJ) * NELEM + e;
    float sF = 0.0f, sR = 0.0f;
    #pragma unroll 5
    for (int i = 0; i < GPJ; ++i) {
        sF += pF[(size_t)i * NELEM];
        sR += pR[(size_t)i * NELEM];
    }
    pb[(size_t)(2 * j + 0) * NELEM + e] = sF;
    pb[(size_t)(2 * j + 1) * NELEM + e] = sR;
}

// ---------------- K2b: finish sums, per-e dot/ff, block reduce ----------------
__global__ void dot_kernel(const float* __restrict__ pb, double* __restrict__ k2out)
{
    __shared__ double red[2][4];
    const int t = threadIdx.x;
    const int e = blockIdx.x * 256 + t;
    float sF = 0.0f, sR = 0.0f;
    #pragma unroll
    for (int j = 0; j < NJ; ++j) {
        sF += pb[(size_t)(2 * j + 0) * NELEM + e];
        sR += pb[(size_t)(2 * j + 1) * NELEM + e];
    }
    double d  = (double)sF * (double)sR;
    double f2 = (double)sF * (double)sF;
    #pragma unroll
    for (int off = 32; off; off >>= 1) {
        d  += __shfl_down(d,  off, 64);
        f2 += __shfl_down(f2, off, 64);
    }
    if ((t & 63) == 0) { red[0][t >> 6] = d; red[1][t >> 6] = f2; }
    __syncthreads();
    if (t == 0) {
        k2out[2 * blockIdx.x + 0] = red[0][0] + red[0][1] + red[0][2] + red[0][3];
        k2out[2 * blockIdx.x + 1] = red[1][0] + red[1][1] + red[1][2] + red[1][3];
    }
}

// ---------------- K3: final combine in double ----------------
__global__ void final_kernel(const double* __restrict__ k2out, const float* __restrict__ saArr,
                             float* __restrict__ out)
{
    __shared__ double red[4][4];
    const int t = threadIdx.x;
    double d = 0.0, f2 = 0.0, sf = 0.0, sr = 0.0;
    if (t < NFREQ) { d = k2out[2 * t]; f2 = k2out[2 * t + 1]; }
    for (int i = t; i < NSEG; i += 256) {
        sf += (double)saArr[i];
        sr += (double)saArr[NSEG + i];
    }
    #pragma unroll
    for (int off = 32; off; off >>= 1) {
        d  += __shfl_down(d,  off, 64);
        f2 += __shfl_down(f2, off, 64);
        sf += __shfl_down(sf, off, 64);
        sr += __shfl_down(sr, off, 64);
    }
    const int w = t >> 6;
    if ((t & 63) == 0) { red[0][w] = d; red[1][w] = f2; red[2][w] = sf; red[3][w] = sr; }
    __syncthreads();
    if (t == 0) {
        double D  = red[0][0] + red[0][1] + red[0][2] + red[0][3];
        double FF = red[1][0] + red[1][1] + red[1][2] + red[1][3];
        double SF = red[2][0] + red[2][1] + red[2][2] + red[2][3];
        double SR = red[3][0] + red[3][1] + red[3][2] + red[3][3];

        const double n    = (double)NELEM;
        const double nseg = (double)NSEG;
        const double m    = nseg * (nseg - 1.0) * 0.5;

        out[0] = (float)((SF / nseg + SR / nseg - 2.0 * D / (nseg * nseg)) / n);
        out[1] = (float)((nseg * SF - FF) / (n * m));
    }
}

extern "C" void kernel_launch(void* const* d_in, const int* in_sizes, int n_in,
                              void* d_out, int out_size, void* d_ws, size_t ws_size,
                              hipStream_t stream) {
    const float* fake = (const float*)d_in[0];
    const float* real = (const float*)d_in[1];
    float* ws  = (float*)d_ws;
    float* out = (float*)d_out;

    // ws layout (floats): part[1600*13056] | saArr[1600] | pb[2*NJ*13056] | k2out (doubles)
    // Total ~85.3 MB; R2 ran this exact footprint (path A confirmed via WRITE_SIZE).
    const size_t SA_FL = (size_t)NBLK * NELEM;            // 20,889,600
    const size_t PB_FL = SA_FL + NBLK;
    const size_t K2_BY = (PB_FL + (size_t)2 * NJ * NELEM) * 4;  // 8B-aligned

    float*  sa = ws + SA_FL;
    float*  pb = ws + PB_FL;
    double* k2 = (double*)((char*)d_ws + K2_BY);

    psd_seg_kernel<<<NBLK, 256, 0, stream>>>(fake, real, ws, sa);
    reduce_part_kernel<<<dim3(NFREQ, NJ), 256, 0, stream>>>(ws, pb);
    dot_kernel<<<NFREQ, 256, 0, stream>>>(pb, k2);
    final_kernel<<<1, 256, 0, stream>>>(k2, sa, out);
}

// Round 5
// 415.558 us; speedup vs baseline: 1.5201x; 1.5201x over previous
//
#include <hip/hip_runtime.h>

#define NSEG   800
#define BATCH  256
#define NFREQ  51
#define NELEM  (BATCH*NFREQ)      // 13056
#define NSAMP  80000
#define NBLK   (2*NSEG)           // 1600 K1 blocks (1 segment each)
#define NJ     8                  // reduce split
#define GPJ    (NSEG/NJ)          // 100 blocks per slab
#define XSTR   68                 // LDS row stride (words): 16B-aligned, conflict-free

typedef __attribute__((ext_vector_type(8))) short  short8;   // 8 bf16 = 4 VGPR
typedef __attribute__((ext_vector_type(4))) float  float4v;  // MFMA acc

// ---------------- compile-time window (double Taylor, exact to fp32) ----------------
constexpr double TCPI  = 3.14159265358979323846264338327950288;
constexpr double TC2PI = 6.28318530717958647692528676655900577;

constexpr double taylor_cos(double y) {   // |y| <= pi
    double y2 = y * y, term = 1.0, sum = 1.0;
    for (int j = 1; j <= 26; ++j) { term *= -y2 / (double)((2*j-1)*(2*j)); sum += term; }
    return sum;
}
constexpr double cos_k(int k) {           // cos(2*pi*(k%100)/100)
    return -taylor_cos(TC2PI * (double)(k % 100) / 100.0 - TCPI);
}
struct WinT { float w[128]; };
constexpr WinT make_win() {
    WinT t{};
    for (int k = 0; k < 128; ++k) t.w[k] = (k < 100) ? (float)(1.0 - cos_k(k)) : 0.0f;
    return t;
}
__device__ const WinT d_wt = make_win();

// ---------------- bf16 helpers (RN-even) ----------------
__device__ __forceinline__ unsigned short f2bf(float x) {
    unsigned int u = __float_as_uint(x);
    return (unsigned short)((u + 0x7FFFu + ((u >> 16) & 1u)) >> 16);
}
__device__ __forceinline__ float bf2f(unsigned short h) {
    return __uint_as_float(((unsigned int)h) << 16);
}

// ---------------- K0: twiddle tables in MFMA B-frag order ----------------
// tw[pt][lane][j], pt=(kt*4+nt)*4+typ, typ: 0=Chi 1=Clo 2=Shi 3=Slo
// B[k=quad*8+j][n=lane&15] = trig(2*pi*n_global*f/100); zero for f>=51 or n>=100
__global__ void gen_tw_kernel(unsigned short* __restrict__ tw)
{
    int tid  = blockIdx.x * 256 + threadIdx.x;   // < 4096
    int lane = tid & 63, pt = tid >> 6;          // pt < 64
    int typ = pt & 3, nt = (pt >> 2) & 3, kt = pt >> 4;
    int f    = nt * 16 + (lane & 15);
    #pragma unroll
    for (int j = 0; j < 8; ++j) {
        int n = kt * 32 + (lane >> 4) * 8 + j;
        unsigned short outv = 0;
        if (f < 51 && n < 100) {
            int m = (n * f) % 100;
            double ang = TC2PI * (double)m / 100.0;
            float c = (float)((typ < 2) ? cos(ang) : sin(ang));
            unsigned short h = f2bf(c);
            outv = (typ & 1) ? f2bf(c - bf2f(h)) : h;
        }
        tw[(pt << 9) + (lane << 3) + j] = outv;
    }
}

// ---------------- K1: per-segment MFMA DFT -> PSD -> log -> normalize ----------------
__global__ void __launch_bounds__(512) __attribute__((amdgpu_waves_per_eu(4, 4)))
psd_seg_kernel(const float* __restrict__ fake, const float* __restrict__ real,
               float* __restrict__ part, float* __restrict__ saArr,
               const unsigned short* __restrict__ tw)
{
    __shared__ float xs[BATCH * XSTR];    // 69632 B; reused as L-buffer (13056 floats)
    __shared__ float pmn[512], pmx[512];
    __shared__ float mnv[256], invv[256];
    __shared__ float red8[8];

    const int bx = blockIdx.x;
    const int a  = bx >= NSEG;
    const int s  = a ? bx - NSEG : bx;
    const int t  = threadIdx.x;
    const int lane = t & 63, wv = t >> 6;
    const int col = lane & 15, quad = lane >> 4;
    const float4* __restrict__ src4 = (const float4*)(a ? real : fake);
    const float4* __restrict__ w4   = (const float4*)d_wt.w;
    float4* lds4 = (float4*)xs;           // rows at stride 17 float4

    float4v accRe[2][4] = {};
    float4v accIm[2][4] = {};

    #pragma unroll
    for (int phase = 0; phase < 2; ++phase) {
        // ---- stage 256 rows x 64 k-slots (fp32, windowed), coalesced float4 ----
        if (phase == 0) {
            #pragma unroll
            for (int it = 0; it < 8; ++it) {
                int idx = t + it * 512;                  // < 4096
                int row = idx >> 4, kk4 = idx & 15;      // samples 4*kk4..+3
                float4 v = src4[(size_t)row * (NSAMP/4) + s * 25 + kk4];
                float4 ww = w4[kk4];
                float4 o;
                o.x = fmaxf(v.x, 1e-6f) * ww.x;  o.y = fmaxf(v.y, 1e-6f) * ww.y;
                o.z = fmaxf(v.z, 1e-6f) * ww.z;  o.w = fmaxf(v.w, 1e-6f) * ww.w;
                lds4[row * 17 + kk4] = o;
            }
        } else {
            #pragma unroll
            for (int it = 0; it < 8; ++it) {
                int idx = t + it * 512;
                int row = idx >> 4, kk4 = idx & 15;      // samples 64+4*kk4
                float4 o = {0.0f, 0.0f, 0.0f, 0.0f};
                if (kk4 < 9) {                           // samples 64..99 real
                    float4 v = src4[(size_t)row * (NSAMP/4) + s * 25 + 16 + kk4];
                    float4 ww = w4[16 + kk4];
                    o.x = fmaxf(v.x, 1e-6f) * ww.x;  o.y = fmaxf(v.y, 1e-6f) * ww.y;
                    o.z = fmaxf(v.z, 1e-6f) * ww.z;  o.w = fmaxf(v.w, 1e-6f) * ww.w;
                }
                lds4[row * 17 + kk4] = o;
            }
        }
        __syncthreads();

        // ---- 2 k-steps of 32: build X hi/lo frags, MFMA vs twiddle frags ----
        #pragma unroll
        for (int kl = 0; kl < 2; ++kl) {
            const int kt = phase * 2 + kl;
            #pragma unroll
            for (int mt = 0; mt < 2; ++mt) {
                const int row = 32 * wv + 16 * mt + col;     // A: m = lane&15
                const float* px = &xs[row * XSTR + kl * 32 + quad * 8];
                float4 pa = *(const float4*)px;
                float4 pq = *(const float4*)(px + 4);
                short8 xh, xl;
                {
                    float vv[8] = {pa.x, pa.y, pa.z, pa.w, pq.x, pq.y, pq.z, pq.w};
                    #pragma unroll
                    for (int j = 0; j < 8; ++j) {
                        unsigned short h = f2bf(vv[j]);
                        xh[j] = (short)h;
                        xl[j] = (short)f2bf(vv[j] - bf2f(h));
                    }
                }
                #pragma unroll
                for (int nt = 0; nt < 4; ++nt) {
                    const unsigned short* bp = tw + (size_t)((kt * 4 + nt) * 4) * 512 + (lane << 3);
                    short8 bCh = *(const short8*)(bp);
                    short8 bCl = *(const short8*)(bp + 512);
                    short8 bSh = *(const short8*)(bp + 1024);
                    short8 bSl = *(const short8*)(bp + 1536);
                    accRe[mt][nt] = __builtin_amdgcn_mfma_f32_16x16x32_bf16(xh, bCh, accRe[mt][nt], 0, 0, 0);
                    accRe[mt][nt] = __builtin_amdgcn_mfma_f32_16x16x32_bf16(xl, bCh, accRe[mt][nt], 0, 0, 0);
                    accRe[mt][nt] = __builtin_amdgcn_mfma_f32_16x16x32_bf16(xh, bCl, accRe[mt][nt], 0, 0, 0);
                    accIm[mt][nt] = __builtin_amdgcn_mfma_f32_16x16x32_bf16(xh, bSh, accIm[mt][nt], 0, 0, 0);
                    accIm[mt][nt] = __builtin_amdgcn_mfma_f32_16x16x32_bf16(xl, bSh, accIm[mt][nt], 0, 0, 0);
                    accIm[mt][nt] = __builtin_amdgcn_mfma_f32_16x16x32_bf16(xh, bSl, accIm[mt][nt], 0, 0, 0);
                }
            }
        }
        __syncthreads();
    }

    // ---- PSD -> signed clamp log -> L buffer (xs reused, flat e = row*51 + f) ----
    // C/D layout: col = lane&15, row = quad*4 + reg  [verified m89/m91]
    #pragma unroll
    for (int mt = 0; mt < 2; ++mt) {
        #pragma unroll
        for (int nt = 0; nt < 4; ++nt) {
            const int f = nt * 16 + col;
            if (f < 51) {
                #pragma unroll
                for (int reg = 0; reg < 4; ++reg) {
                    const int row = 32 * wv + 16 * mt + quad * 4 + reg;
                    float re = accRe[mt][nt][reg], im = accIm[mt][nt][reg];
                    float p  = fmaf(re, re, im * im);
                    p        = fmaxf(p, 1e-38f);
                    float lv = __logf(p);
                    float al = fmaxf(fabsf(lv), 1e-6f);
                    xs[row * 51 + f] = (lv > 0.0f) ? al : ((lv < 0.0f) ? -al : 0.0f);
                }
            }
        }
    }
    __syncthreads();

    // ---- group min/max (group c over flat {r*256+c}), split r across 2 half-blocks ----
    const int tcol = t & 255, half = t >> 8;
    const int r0 = half ? 26 : 0, r1 = half ? 51 : 26;
    {
        float mn = 1e30f, mx = -1e30f;
        for (int r = r0; r < r1; ++r) {
            float v = xs[r * BATCH + tcol];
            mn = fminf(mn, v);
            mx = fmaxf(mx, v);
        }
        pmn[half * 256 + tcol] = mn;
        pmx[half * 256 + tcol] = mx;
    }
    __syncthreads();
    if (t < 256) {
        float m2 = fminf(pmn[t], pmn[256 + t]);
        float M2 = fmaxf(pmx[t], pmx[256 + t]);
        mnv[t]  = m2;
        invv[t] = 1.0f / (M2 - m2);
    }
    __syncthreads();

    // ---- normalize + coalesced dump + ssq ----
    float ssq = 0.0f;
    {
        const float mnl = mnv[tcol], invl = invv[tcol];
        float* __restrict__ dst = part + (size_t)bx * NELEM;
        for (int r = r0; r < r1; ++r) {
            float F = (xs[r * BATCH + tcol] - mnl) * invl;
            ssq = fmaf(F, F, ssq);
            dst[r * BATCH + tcol] = F;
        }
    }
    #pragma unroll
    for (int off = 32; off; off >>= 1) ssq += __shfl_down(ssq, off, 64);
    if (lane == 0) red8[wv] = ssq;
    __syncthreads();
    if (t == 0) {
        float acc = 0.0f;
        #pragma unroll
        for (int i = 0; i < 8; ++i) acc += red8[i];
        saArr[bx] = acc;
    }
}

// ---------------- K2a: partial column sums over 100-block slabs ----------------
__global__ void reduce_part_kernel(const float* __restrict__ part, float* __restrict__ pb)
{
    const int e = blockIdx.x * 256 + threadIdx.x;   // < 13056
    const int j = blockIdx.y;                        // < NJ
    const float* __restrict__ pF = part + (size_t)(j * GPJ) * NELEM + e;
    const float* __restrict__ pR = part + (size_t)(NSEG + j * GPJ) * NELEM + e;
    float sF = 0.0f, sR = 0.0f;
    #pragma unroll 5
    for (int i = 0; i < GPJ; ++i) {
        sF += pF[(size_t)i * NELEM];
        sR += pR[(size_t)i * NELEM];
    }
    pb[(size_t)(2 * j + 0) * NELEM + e] = sF;
    pb[(size_t)(2 * j + 1) * NELEM + e] = sR;
}

// ---------------- K2b: finish sums, per-e dot/ff, block reduce ----------------
__global__ void dot_kernel(const float* __restrict__ pb, double* __restrict__ k2out)
{
    __shared__ double red[2][4];
    const int t = threadIdx.x;
    const int e = blockIdx.x * 256 + t;
    float sF = 0.0f, sR = 0.0f;
    #pragma unroll
    for (int j = 0; j < NJ; ++j) {
        sF += pb[(size_t)(2 * j + 0) * NELEM + e];
        sR += pb[(size_t)(2 * j + 1) * NELEM + e];
    }
    double d  = (double)sF * (double)sR;
    double f2 = (double)sF * (double)sF;
    #pragma unroll
    for (int off = 32; off; off >>= 1) {
        d  += __shfl_down(d,  off, 64);
        f2 += __shfl_down(f2, off, 64);
    }
    if ((t & 63) == 0) { red[0][t >> 6] = d; red[1][t >> 6] = f2; }
    __syncthreads();
    if (t == 0) {
        k2out[2 * blockIdx.x + 0] = red[0][0] + red[0][1] + red[0][2] + red[0][3];
        k2out[2 * blockIdx.x + 1] = red[1][0] + red[1][1] + red[1][2] + red[1][3];
    }
}

// ---------------- K3: final combine in double ----------------
__global__ void final_kernel(const double* __restrict__ k2out, const float* __restrict__ saArr,
                             float* __restrict__ out)
{
    __shared__ double red[4][4];
    const int t = threadIdx.x;
    double d = 0.0, f2 = 0.0, sf = 0.0, sr = 0.0;
    if (t < NFREQ) { d = k2out[2 * t]; f2 = k2out[2 * t + 1]; }
    for (int i = t; i < NSEG; i += 256) {
        sf += (double)saArr[i];
        sr += (double)saArr[NSEG + i];
    }
    #pragma unroll
    for (int off = 32; off; off >>= 1) {
        d  += __shfl_down(d,  off, 64);
        f2 += __shfl_down(f2, off, 64);
        sf += __shfl_down(sf, off, 64);
        sr += __shfl_down(sr, off, 64);
    }
    const int w = t >> 6;
    if ((t & 63) == 0) { red[0][w] = d; red[1][w] = f2; red[2][w] = sf; red[3][w] = sr; }
    __syncthreads();
    if (t == 0) {
        double D  = red[0][0] + red[0][1] + red[0][2] + red[0][3];
        double FF = red[1][0] + red[1][1] + red[1][2] + red[1][3];
        double SF = red[2][0] + red[2][1] + red[2][2] + red[2][3];
        double SR = red[3][0] + red[3][1] + red[3][2] + red[3][3];

        const double n    = (double)NELEM;
        const double nseg = (double)NSEG;
        const double m    = nseg * (nseg - 1.0) * 0.5;

        out[0] = (float)((SF / nseg + SR / nseg - 2.0 * D / (nseg * nseg)) / n);
        out[1] = (float)((nseg * SF - FF) / (n * m));
    }
}

extern "C" void kernel_launch(void* const* d_in, const int* in_sizes, int n_in,
                              void* d_out, int out_size, void* d_ws, size_t ws_size,
                              hipStream_t stream) {
    const float* fake = (const float*)d_in[0];
    const float* real = (const float*)d_in[1];
    float* ws  = (float*)d_ws;
    float* out = (float*)d_out;

    // ws (floats): part[1600*13056] | saArr[1600] | pb[2*NJ*13056] | k2out (doubles) | tw (64KB)
    const size_t SA_FL = (size_t)NBLK * NELEM;            // 20,889,600
    const size_t PB_FL = SA_FL + NBLK;
    const size_t K2_BY = (PB_FL + (size_t)2 * NJ * NELEM) * 4;         // 8B-aligned
    const size_t TW_BY = (K2_BY + 2 * NFREQ * sizeof(double) + 63) & ~(size_t)63;

    float*          sa = ws + SA_FL;
    float*          pb = ws + PB_FL;
    double*         k2 = (double*)((char*)d_ws + K2_BY);
    unsigned short* tw = (unsigned short*)((char*)d_ws + TW_BY);

    gen_tw_kernel<<<16, 256, 0, stream>>>(tw);
    psd_seg_kernel<<<NBLK, 512, 0, stream>>>(fake, real, ws, sa, tw);
    reduce_part_kernel<<<dim3(NFREQ, NJ), 256, 0, stream>>>(ws, pb);
    dot_kernel<<<NFREQ, 256, 0, stream>>>(pb, k2);
    final_kernel<<<1, 256, 0, stream>>>(k2, sa, out);
}

// Round 6
// 276.413 us; speedup vs baseline: 2.2853x; 1.5034x over previous
//
#include <hip/hip_runtime.h>

#define NSEG   800
#define BATCH  256
#define NFREQ  51
#define NELEM  (BATCH*NFREQ)      // 13056
#define NSAMP  80000
#define NBLK   (2*NSEG)           // 1600 K1 blocks (1 segment each)
#define NJ     16                 // reduce split
#define GPJ    (NSEG/NJ)          // 50 blocks per slab
#define XSTR   136                // shorts per staged row (16B-mult, covers k 0..127 + pad)

typedef __attribute__((ext_vector_type(8))) short          short8;    // 8 bf16 = 4 VGPR
typedef __attribute__((ext_vector_type(4))) float          float4v;   // MFMA acc
typedef __attribute__((ext_vector_type(4))) unsigned short ushort4v;

// ---------------- compile-time window (double Taylor, exact to fp32) ----------------
constexpr double TCPI  = 3.14159265358979323846264338327950288;
constexpr double TC2PI = 6.28318530717958647692528676655900577;

constexpr double taylor_cos(double y) {   // |y| <= pi
    double y2 = y * y, term = 1.0, sum = 1.0;
    for (int j = 1; j <= 26; ++j) { term *= -y2 / (double)((2*j-1)*(2*j)); sum += term; }
    return sum;
}
constexpr double cos_k(int k) {           // cos(2*pi*(k%100)/100)
    return -taylor_cos(TC2PI * (double)(k % 100) / 100.0 - TCPI);
}
struct WinT { float w[100]; };
constexpr WinT make_win() {
    WinT t{};
    for (int k = 0; k < 100; ++k) t.w[k] = (float)(1.0 - cos_k(k));   // hann(periodic)*2
    return t;
}
__device__ const WinT d_wt = make_win();

// ---------------- bf16 helpers (RN-even) ----------------
__device__ __forceinline__ unsigned short f2bf(float x) {
    unsigned int u = __float_as_uint(x);
    return (unsigned short)((u + 0x7FFFu + ((u >> 16) & 1u)) >> 16);
}
__device__ __forceinline__ float bf2f(unsigned short h) {
    return __uint_as_float(((unsigned int)h) << 16);
}

// ---------------- K0: twiddle tables in MFMA B-frag order ----------------
// tw[pt][lane][j], pt=(kt*4+nt)*4+typ, typ: 0=Chi 1=Clo 2=Shi 3=Slo
// B[k=quad*8+j][f=lane&15]; zero for f>=51 or k>=100
__global__ void gen_tw_kernel(unsigned short* __restrict__ tw)
{
    int tid  = blockIdx.x * 256 + threadIdx.x;   // < 4096
    int lane = tid & 63, pt = tid >> 6;          // pt < 64
    int typ = pt & 3, nt = (pt >> 2) & 3, kt = pt >> 4;
    int f    = nt * 16 + (lane & 15);
    #pragma unroll
    for (int j = 0; j < 8; ++j) {
        int n = kt * 32 + (lane >> 4) * 8 + j;
        unsigned short outv = 0;
        if (f < 51 && n < 100) {
            int m = (n * f) % 100;
            double ang = TC2PI * (double)m / 100.0;
            float c = (float)((typ < 2) ? cos(ang) : sin(ang));
            unsigned short h = f2bf(c);
            outv = (typ & 1) ? f2bf(c - bf2f(h)) : h;
        }
        tw[(pt << 9) + (lane << 3) + j] = outv;
    }
}

// ---------------- K1: per-segment MFMA DFT (freq-split) -> PSD -> log -> normalize ----------------
// LDS 128 KB -> 1 block/CU -> 2 waves/EU: VGPR budget 256, peak live ~56 -> no spill possible.
__global__ void __launch_bounds__(512) __attribute__((amdgpu_waves_per_eu(2)))
psd_seg_kernel(const float* __restrict__ fake, const float* __restrict__ real,
               float* __restrict__ part, float* __restrict__ saArr,
               const unsigned short* __restrict__ tw)
{
    __shared__ unsigned short xsh[BATCH * XSTR];   // 69632 B, bf16-hi of windowed x
    __shared__ float Lb[NELEM];                    // 52224 B, signed-clamped log PSD
    __shared__ float pmn[512], pmx[512];
    __shared__ float mnv[256], invv[256];
    __shared__ float red8[8];

    const int bx = blockIdx.x;
    const int a  = bx >= NSEG;
    const int s  = a ? bx - NSEG : bx;
    const int t  = threadIdx.x;
    const int lane = t & 63, wv = t >> 6;
    const int col = lane & 15, quad = lane >> 4;
    const float4* __restrict__ src4 = (const float4*)(a ? real : fake);
    const float4* __restrict__ w4   = (const float4*)d_wt.w;

    // ---- stage: 6400 coalesced float4 loads -> clamp/window -> bf16 short4 stores ----
    #pragma unroll
    for (int it = 0; it < 13; ++it) {
        int idx = t + it * 512;
        if (idx < 6400) {
            int row = idx / 25, q = idx - row * 25;          // q-th float4 of row
            float4 v  = src4[(size_t)row * (NSAMP / 4) + s * 25 + q];
            float4 ww = w4[q];
            ushort4v o;
            o.x = f2bf(fmaxf(v.x, 1e-6f) * ww.x);
            o.y = f2bf(fmaxf(v.y, 1e-6f) * ww.y);
            o.z = f2bf(fmaxf(v.z, 1e-6f) * ww.z);
            o.w = f2bf(fmaxf(v.w, 1e-6f) * ww.w);
            *(ushort4v*)(xsh + row * XSTR + 4 * q) = o;      // 8B-aligned
        }
    }
    // ---- zero-pad k-slots 100..127 (7 short4 per row) ----
    #pragma unroll
    for (int it = 0; it < 4; ++it) {
        int idx = t + it * 512;
        if (idx < 1792) {
            int row = idx / 7, q = idx - row * 7;
            ushort4v z = {0, 0, 0, 0};
            *(ushort4v*)(xsh + row * XSTR + 100 + 4 * q) = z;
        }
    }
    __syncthreads();

    // ---- two frequency passes over the same staged X: acc = 32 VGPRs per pass ----
    #pragma unroll 1
    for (int fh = 0; fh < 2; ++fh) {
        float4v accRe[2][2] = {};
        float4v accIm[2][2] = {};
        #pragma unroll
        for (int kt = 0; kt < 4; ++kt) {
            #pragma unroll
            for (int mt = 0; mt < 2; ++mt) {
                const int row = 32 * wv + 16 * mt + col;     // A: m = lane&15
                short8 xa = *(const short8*)(xsh + row * XSTR + kt * 32 + quad * 8);
                #pragma unroll
                for (int ntl = 0; ntl < 2; ++ntl) {
                    const int nt = fh * 2 + ntl;
                    const unsigned short* bp = tw + (size_t)((kt * 4 + nt) * 4) * 512 + (lane << 3);
                    short8 bCh = *(const short8*)(bp);
                    short8 bCl = *(const short8*)(bp + 512);
                    accRe[mt][ntl] = __builtin_amdgcn_mfma_f32_16x16x32_bf16(xa, bCh, accRe[mt][ntl], 0, 0, 0);
                    accRe[mt][ntl] = __builtin_amdgcn_mfma_f32_16x16x32_bf16(xa, bCl, accRe[mt][ntl], 0, 0, 0);
                    short8 bSh = *(const short8*)(bp + 1024);
                    short8 bSl = *(const short8*)(bp + 1536);
                    accIm[mt][ntl] = __builtin_amdgcn_mfma_f32_16x16x32_bf16(xa, bSh, accIm[mt][ntl], 0, 0, 0);
                    accIm[mt][ntl] = __builtin_amdgcn_mfma_f32_16x16x32_bf16(xa, bSl, accIm[mt][ntl], 0, 0, 0);
                }
            }
        }
        // ---- PSD -> signed clamp log -> Lb (C/D layout: col=lane&15, row=quad*4+reg) ----
        #pragma unroll
        for (int mt = 0; mt < 2; ++mt) {
            #pragma unroll
            for (int ntl = 0; ntl < 2; ++ntl) {
                const int f = (fh * 2 + ntl) * 16 + col;
                if (f < 51) {
                    #pragma unroll
                    for (int reg = 0; reg < 4; ++reg) {
                        const int row = 32 * wv + 16 * mt + quad * 4 + reg;
                        float re = accRe[mt][ntl][reg], im = accIm[mt][ntl][reg];
                        float p  = fmaf(re, re, im * im);
                        p        = fmaxf(p, 1e-38f);
                        float lv = __logf(p);
                        float al = fmaxf(fabsf(lv), 1e-6f);
                        Lb[row * 51 + f] = (lv > 0.0f) ? al : ((lv < 0.0f) ? -al : 0.0f);
                    }
                }
            }
        }
        // no barrier needed: xsh read-only here, Lb regions disjoint per thread
    }
    __syncthreads();

    // ---- group min/max (group c over flat {r*256+c}), r split across 2 half-blocks ----
    const int tcol = t & 255, half = t >> 8;
    const int r0 = half ? 26 : 0, r1 = half ? 51 : 26;
    {
        float mn = 1e30f, mx = -1e30f;
        for (int r = r0; r < r1; ++r) {
            float v = Lb[r * BATCH + tcol];
            mn = fminf(mn, v);
            mx = fmaxf(mx, v);
        }
        pmn[half * 256 + tcol] = mn;
        pmx[half * 256 + tcol] = mx;
    }
    __syncthreads();
    if (t < 256) {
        float m2 = fminf(pmn[t], pmn[256 + t]);
        float M2 = fmaxf(pmx[t], pmx[256 + t]);
        mnv[t]  = m2;
        invv[t] = 1.0f / (M2 - m2);
    }
    __syncthreads();

    // ---- normalize + coalesced dump + ssq ----
    float ssq = 0.0f;
    {
        const float mnl = mnv[tcol], invl = invv[tcol];
        float* __restrict__ dst = part + (size_t)bx * NELEM;
        for (int r = r0; r < r1; ++r) {
            float F = (Lb[r * BATCH + tcol] - mnl) * invl;
            ssq = fmaf(F, F, ssq);
            dst[r * BATCH + tcol] = F;
        }
    }
    #pragma unroll
    for (int off = 32; off; off >>= 1) ssq += __shfl_down(ssq, off, 64);
    if (lane == 0) red8[wv] = ssq;
    __syncthreads();
    if (t == 0) {
        float acc = 0.0f;
        #pragma unroll
        for (int i = 0; i < 8; ++i) acc += red8[i];
        saArr[bx] = acc;
    }
}

// ---------------- K2a: partial column sums over 50-block slabs ----------------
__global__ void reduce_part_kernel(const float* __restrict__ part, float* __restrict__ pb)
{
    const int e = blockIdx.x * 256 + threadIdx.x;   // < 13056
    const int j = blockIdx.y;                        // < NJ
    const float* __restrict__ pF = part + (size_t)(j * GPJ) * NELEM + e;
    const float* __restrict__ pR = part + (size_t)(NSEG + j * GPJ) * NELEM + e;
    float sF = 0.0f, sR = 0.0f;
    #pragma unroll 5
    for (int i = 0; i < GPJ; ++i) {
        sF += pF[(size_t)i * NELEM];
        sR += pR[(size_t)i * NELEM];
    }
    pb[(size_t)(2 * j + 0) * NELEM + e] = sF;
    pb[(size_t)(2 * j + 1) * NELEM + e] = sR;
}

// ---------------- K2b: finish sums, per-e dot/ff, block reduce ----------------
__global__ void dot_kernel(const float* __restrict__ pb, double* __restrict__ k2out)
{
    __shared__ double red[2][4];
    const int t = threadIdx.x;
    const int e = blockIdx.x * 256 + t;
    float sF = 0.0f, sR = 0.0f;
    #pragma unroll
    for (int j = 0; j < NJ; ++j) {
        sF += pb[(size_t)(2 * j + 0) * NELEM + e];
        sR += pb[(size_t)(2 * j + 1) * NELEM + e];
    }
    double d  = (double)sF * (double)sR;
    double f2 = (double)sF * (double)sF;
    #pragma unroll
    for (int off = 32; off; off >>= 1) {
        d  += __shfl_down(d,  off, 64);
        f2 += __shfl_down(f2, off, 64);
    }
    if ((t & 63) == 0) { red[0][t >> 6] = d; red[1][t >> 6] = f2; }
    __syncthreads();
    if (t == 0) {
        k2out[2 * blockIdx.x + 0] = red[0][0] + red[0][1] + red[0][2] + red[0][3];
        k2out[2 * blockIdx.x + 1] = red[1][0] + red[1][1] + red[1][2] + red[1][3];
    }
}

// ---------------- K3: final combine in double ----------------
__global__ void final_kernel(const double* __restrict__ k2out, const float* __restrict__ saArr,
                             float* __restrict__ out)
{
    __shared__ double red[4][4];
    const int t = threadIdx.x;
    double d = 0.0, f2 = 0.0, sf = 0.0, sr = 0.0;
    if (t < NFREQ) { d = k2out[2 * t]; f2 = k2out[2 * t + 1]; }
    for (int i = t; i < NSEG; i += 256) {
        sf += (double)saArr[i];
        sr += (double)saArr[NSEG + i];
    }
    #pragma unroll
    for (int off = 32; off; off >>= 1) {
        d  += __shfl_down(d,  off, 64);
        f2 += __shfl_down(f2, off, 64);
        sf += __shfl_down(sf, off, 64);
        sr += __shfl_down(sr, off, 64);
    }
    const int w = t >> 6;
    if ((t & 63) == 0) { red[0][w] = d; red[1][w] = f2; red[2][w] = sf; red[3][w] = sr; }
    __syncthreads();
    if (t == 0) {
        double D  = red[0][0] + red[0][1] + red[0][2] + red[0][3];
        double FF = red[1][0] + red[1][1] + red[1][2] + red[1][3];
        double SF = red[2][0] + red[2][1] + red[2][2] + red[2][3];
        double SR = red[3][0] + red[3][1] + red[3][2] + red[3][3];

        const double n    = (double)NELEM;
        const double nseg = (double)NSEG;
        const double m    = nseg * (nseg - 1.0) * 0.5;

        out[0] = (float)((SF / nseg + SR / nseg - 2.0 * D / (nseg * nseg)) / n);
        out[1] = (float)((nseg * SF - FF) / (n * m));
    }
}

extern "C" void kernel_launch(void* const* d_in, const int* in_sizes, int n_in,
                              void* d_out, int out_size, void* d_ws, size_t ws_size,
                              hipStream_t stream) {
    const float* fake = (const float*)d_in[0];
    const float* real = (const float*)d_in[1];
    float* ws  = (float*)d_ws;
    float* out = (float*)d_out;

    // ws (floats): part[1600*13056] | saArr[1600] | pb[2*NJ*13056] | k2out (doubles) | tw (64KB)
    const size_t SA_FL = (size_t)NBLK * NELEM;            // 20,889,600
    const size_t PB_FL = SA_FL + NBLK;
    const size_t K2_BY = (PB_FL + (size_t)2 * NJ * NELEM) * 4;         // 8B-aligned
    const size_t TW_BY = (K2_BY + 2 * NFREQ * sizeof(double) + 63) & ~(size_t)63;

    float*          sa = ws + SA_FL;
    float*          pb = ws + PB_FL;
    double*         k2 = (double*)((char*)d_ws + K2_BY);
    unsigned short* tw = (unsigned short*)((char*)d_ws + TW_BY);

    gen_tw_kernel<<<16, 256, 0, stream>>>(tw);
    psd_seg_kernel<<<NBLK, 512, 0, stream>>>(fake, real, ws, sa, tw);
    reduce_part_kernel<<<dim3(NFREQ, NJ), 256, 0, stream>>>(ws, pb);
    dot_kernel<<<NFREQ, 256, 0, stream>>>(pb, k2);
    final_kernel<<<1, 256, 0, stream>>>(k2, sa, out);
}